// Round 1
// baseline (255.385 us; speedup 1.0000x reference)
//
#include <hip/hip_runtime.h>

// AutoregressiveLSTM: B=16384, T=100, HID=10, IN=OUT=4, P=5, Tp=96.
// Mapping: 10 lanes per batch element (lane u owns hidden unit u's 4 gate rows),
// 6 groups per wave (lanes 60-63 idle), 4 waves per block -> 24 batches/block.
// Rollout cells use folded W_comb = W_hh + W_ih@W_lin (y drops off critical path).

#define HIDN 10
#define INPN 4
#define OUTN 4
#define PN   5
#define TN   100
#define TPN  96
#define BN   16384
#define GPB  24   // batches (groups) per 256-thread block

__device__ __forceinline__ float rcpf_(float v) { return __builtin_amdgcn_rcpf(v); }
__device__ __forceinline__ float sig_(float v)  { return rcpf_(1.0f + __expf(-v)); }
__device__ __forceinline__ float tanhf_(float v){ return 1.0f - 2.0f * rcpf_(1.0f + __expf(2.0f * v)); }

__global__ __launch_bounds__(256, 3) void lstm_ar_kernel(
    const float* __restrict__ x,      // [B, T, IN]
    const float* __restrict__ W_ih,   // [40, 4]
    const float* __restrict__ W_hh,   // [40, 10]
    const float* __restrict__ b_ih,   // [40]
    const float* __restrict__ b_hh,   // [40]
    const float* __restrict__ W_lin,  // [4, 10]
    const float* __restrict__ b_lin,  // [4]
    float* __restrict__ out)          // [B*Tp*P*OUT] ++ [B*HID]
{
    __shared__ float s_wlin[OUTN * HIDN];          // 40
    __shared__ float s_blin[OUTN];                 // 4
    __shared__ float s_hbank[GPB][PN][HIDN];       // 24*5*10*4B = 4800B

    const int tid = threadIdx.x;
    if (tid < OUTN * HIDN) s_wlin[tid] = W_lin[tid];
    if (tid < OUTN)        s_blin[tid] = b_lin[tid];
    __syncthreads();

    const int wid = tid >> 6;        // wave id in block
    const int wl  = tid & 63;        // lane in wave
    const int grp = wl / 10;         // group in wave (0..5 valid, 6 = idle lanes)
    const int u   = wl - grp * 10;   // hidden unit owned by this lane
    const int slot  = wid * 6 + grp; // batch slot in block (0..23)
    const int batch = blockIdx.x * GPB + slot;
    if (grp >= 6 || batch >= BN) return;

    const int grpbase = grp * 10;    // first lane of my group (within wave)

    // ---- per-lane weights in registers: rows {u, u+10, u+20, u+30} (i,f,g,o) ----
    float wm[4][HIDN];   // W_hh rows   (main cell)
    float wc[4][HIDN];   // W_comb rows (rollout cells)
    float wih_[4][INPN]; // W_ih rows   (main cell)
    float bm[4], br[4];
    #pragma unroll
    for (int r = 0; r < 4; ++r) {
        const int j = u + r * 10;
        #pragma unroll
        for (int k = 0; k < HIDN; ++k) wm[r][k] = W_hh[j * HIDN + k];
        #pragma unroll
        for (int q = 0; q < INPN; ++q) wih_[r][q] = W_ih[j * INPN + q];
        bm[r] = b_ih[j] + b_hh[j];
        float bb = bm[r];
        #pragma unroll
        for (int q = 0; q < INPN; ++q) bb += wih_[r][q] * s_blin[q];
        br[r] = bb;
        #pragma unroll
        for (int k = 0; k < HIDN; ++k) {
            float wck = wm[r][k];
            #pragma unroll
            for (int q = 0; q < INPN; ++q) wck += wih_[r][q] * s_wlin[q * HIDN + k];
            wc[r][k] = wck;
        }
    }

    const float* xb   = x + (long)batch * TN * INPN;
    float*       outb = out + (long)batch * TPN * PN * OUTN;
    const int pmine = u >> 1;        // which rollout step this lane outputs
    const int opair = (u & 1) * 2;   // which output pair (o, o+1)

    float hm[HIDN];                  // replicated main hidden state
    float cm = 0.0f;
    #pragma unroll
    for (int k = 0; k < HIDN; ++k) hm[k] = 0.0f;

    float4 xcur = *(const float4*)xb;   // x[b][0][:]
    for (int t = 0; t < TPN; ++t) {
        // prefetch next step's input (t+1 <= 96 < T=100, always in-bounds)
        float4 xnext = *(const float4*)(xb + (t + 1) * INPN);

        // ---- main cell: gates = W_ih@x + W_hh@h + b ----
        float g[4];
        #pragma unroll
        for (int r = 0; r < 4; ++r) {
            float a = bm[r] + wih_[r][0] * xcur.x + wih_[r][1] * xcur.y
                            + wih_[r][2] * xcur.z + wih_[r][3] * xcur.w;
            #pragma unroll
            for (int k = 0; k < HIDN; ++k) a += wm[r][k] * hm[k];
            g[r] = a;
        }
        {
            float iv = sig_(g[0]), fv = sig_(g[1]), gv = tanhf_(g[2]), ov = sig_(g[3]);
            cm = fv * cm + iv * gv;
            float hn = ov * tanhf_(cm);
            s_hbank[slot][0][u] = hn;                 // bank h_0[u] for y phase
            #pragma unroll
            for (int k = 0; k < HIDN; ++k) hm[k] = __shfl(hn, grpbase + k, 64);
        }

        // ---- rollout cells: gates = W_comb@h_r + b_r ----
        float hr[HIDN];
        float cr = cm;
        #pragma unroll
        for (int k = 0; k < HIDN; ++k) hr[k] = hm[k];
        #pragma unroll
        for (int p = 1; p < PN; ++p) {
            #pragma unroll
            for (int r = 0; r < 4; ++r) {
                float a = br[r];
                #pragma unroll
                for (int k = 0; k < HIDN; ++k) a += wc[r][k] * hr[k];
                g[r] = a;
            }
            float iv = sig_(g[0]), fv = sig_(g[1]), gv = tanhf_(g[2]), ov = sig_(g[3]);
            cr = fv * cr + iv * gv;
            float hn = ov * tanhf_(cr);
            s_hbank[slot][p][u] = hn;                 // bank h_p[u]
            if (p < PN - 1) {
                #pragma unroll
                for (int k = 0; k < HIDN; ++k) hr[k] = __shfl(hn, grpbase + k, 64);
            }
        }

        // ---- y phase (off critical path): lane u -> y[pmine][opair..opair+1] ----
        float y0 = s_blin[opair];
        float y1 = s_blin[opair + 1];
        #pragma unroll
        for (int k = 0; k < HIDN; ++k) {
            float hk = s_hbank[slot][pmine][k];
            y0 += s_wlin[opair * HIDN + k] * hk;
            y1 += s_wlin[opair * HIDN + HIDN + k] * hk;
        }
        float2 yv; yv.x = y0; yv.y = y1;
        // group writes 20 consecutive floats: lane u owns floats {2u, 2u+1}
        *(float2*)(outb + t * PN * OUTN + 2 * u) = yv;

        xcur = xnext;
    }

    // ---- final cell state c: [1, B, HID] appended after final_output ----
    out[(long)BN * TPN * PN * OUTN + (long)batch * HIDN + u] = cm;
}

extern "C" void kernel_launch(void* const* d_in, const int* in_sizes, int n_in,
                              void* d_out, int out_size, void* d_ws, size_t ws_size,
                              hipStream_t stream) {
    const float* x     = (const float*)d_in[0];
    const float* W_ih  = (const float*)d_in[1];
    const float* W_hh  = (const float*)d_in[2];
    const float* b_ih  = (const float*)d_in[3];
    const float* b_hh  = (const float*)d_in[4];
    const float* W_lin = (const float*)d_in[5];
    const float* b_lin = (const float*)d_in[6];
    float* out = (float*)d_out;

    const int grid = (BN + GPB - 1) / GPB;  // 683 blocks of 256 threads
    lstm_ar_kernel<<<grid, 256, 0, stream>>>(x, W_ih, W_hh, b_ih, b_hh, W_lin, b_lin, out);
}

// Round 2
// 249.364 us; speedup vs baseline: 1.0241x; 1.0241x over previous
//
#include <hip/hip_runtime.h>

// AutoregressiveLSTM: B=16384, T=100, HID=10, IN=OUT=4, P=5, Tp=96.
// Mapping: 10 lanes per batch element (lane u owns hidden unit u's 4 gate rows
// i,f,g,o), 6 groups/wave, 4 waves/block -> 24 batches per 256-thread block.
// Rollout cells use folded W_comb = W_hh + W_ih@W_lin (y off the critical path).
// This revision: packed-f32 FMAs (v_pk_fma_f32), exp2-prescaled activations,
// wide LDS h-broadcast (b128 reads) instead of ds_bpermute, W_lin in registers.

#define HIDN 10
#define INPN 4
#define OUTN 4
#define PN   5
#define TN   100
#define TPN  96
#define BN   16384
#define GPB  24   // batches (groups) per 256-thread block

typedef float v2f __attribute__((ext_vector_type(2)));

__device__ __forceinline__ float rcpf_(float v) { return __builtin_amdgcn_rcpf(v); }
// g pre-scaled by log2(e):  sigmoid(x) = 1/(1+2^(-g))
__device__ __forceinline__ float sig2_(float g)  { return rcpf_(1.0f + exp2f(-g)); }
// g pre-scaled by 2*log2(e): tanh(x) = 1 - 2/(1+2^g)
__device__ __forceinline__ float tanh2_(float g) { return fmaf(-2.0f, rcpf_(1.0f + exp2f(g)), 1.0f); }

#define K2L2E 2.88539008177792681472f  // 2*log2(e), for tanh(c)

__global__ __launch_bounds__(256, 2) void lstm_ar_kernel(
    const float* __restrict__ x,      // [B, T, IN]
    const float* __restrict__ W_ih,   // [40, 4]
    const float* __restrict__ W_hh,   // [40, 10]
    const float* __restrict__ b_ih,   // [40]
    const float* __restrict__ b_hh,   // [40]
    const float* __restrict__ W_lin,  // [4, 10]
    const float* __restrict__ b_lin,  // [4]
    float* __restrict__ out)          // [B*Tp*P*OUT] ++ [B*HID]
{
    // h bank: row stride 20 floats (80B, 16B-aligned), slot stride 100 floats.
    // Cell-phase b128 reads: 6 groups land on distinct 16B bank-slots -> conflict-free.
    __shared__ __align__(16) float s_h[GPB][PN][20];

    const int tid = threadIdx.x;
    const int wid = tid >> 6;
    const int wl  = tid & 63;
    const int grp = wl / 10;
    const int u   = wl - grp * 10;
    const int slot  = wid * 6 + grp;
    const int batch = blockIdx.x * GPB + slot;
    if (grp >= 6 || batch >= BN) return;

    // ---- build per-lane weight registers (rows u, u+10, u+20, u+30) ----
    const float L2E = 1.44269504088896340736f;
    const float rs[4] = { L2E, L2E, 2.0f * L2E, L2E };  // row pre-scales (i,f,g,o)

    v2f  wm2[4][5];   // scaled W_hh rows      (main cell)
    v2f  wc2[4][5];   // scaled W_comb rows    (rollout cells)
    v2f  wih2[4][2];  // scaled W_ih rows      (main cell)
    float bm[4], br[4];
    #pragma unroll
    for (int r = 0; r < 4; ++r) {
        const int j = u + r * 10;
        float wmr[HIDN], wihr[INPN];
        #pragma unroll
        for (int k = 0; k < HIDN; ++k) wmr[k] = W_hh[j * HIDN + k];
        #pragma unroll
        for (int q = 0; q < INPN; ++q) wihr[q] = W_ih[j * INPN + q];
        float bmr = b_ih[j] + b_hh[j];
        float brr = bmr;
        #pragma unroll
        for (int q = 0; q < INPN; ++q) brr += wihr[q] * b_lin[q];
        #pragma unroll
        for (int k = 0; k < HIDN; ++k) {
            float wck = wmr[k];
            #pragma unroll
            for (int q = 0; q < INPN; ++q) wck += wihr[q] * W_lin[q * HIDN + k];
            // pack scaled
            if (k & 1) {
                wm2[r][k >> 1].y = wmr[k] * rs[r];
                wc2[r][k >> 1].y = wck    * rs[r];
            } else {
                wm2[r][k >> 1].x = wmr[k] * rs[r];
                wc2[r][k >> 1].x = wck    * rs[r];
            }
        }
        #pragma unroll
        for (int q = 0; q < INPN; ++q) {
            if (q & 1) wih2[r][q >> 1].y = wihr[q] * rs[r];
            else       wih2[r][q >> 1].x = wihr[q] * rs[r];
        }
        bm[r] = bmr * rs[r];
        br[r] = brr * rs[r];
    }

    // ---- y weights in registers: lane outputs y[pmine][opair..opair+1] ----
    const int pmine = u >> 1;
    const int opair = (u & 1) * 2;
    v2f yl0[5], yl1[5];
    #pragma unroll
    for (int k = 0; k < HIDN; k += 2) {
        yl0[k >> 1] = v2f{ W_lin[opair * HIDN + k],        W_lin[opair * HIDN + k + 1] };
        yl1[k >> 1] = v2f{ W_lin[(opair + 1) * HIDN + k],  W_lin[(opair + 1) * HIDN + k + 1] };
    }
    const float yb0 = b_lin[opair];
    const float yb1 = b_lin[opair + 1];

    const float* xb   = x + (long)batch * TN * INPN;
    float*       outb = out + (long)batch * TPN * PN * OUTN;

    v2f hm2[5];
    float cm = 0.0f;
    #pragma unroll
    for (int k = 0; k < 5; ++k) hm2[k] = v2f{0.0f, 0.0f};

    float4 xcur = *(const float4*)xb;
    for (int t = 0; t < TPN; ++t) {
        float4 xnext = *(const float4*)(xb + (t + 1) * INPN);  // t+1 <= 96 < T

        // ---- main cell ----
        v2f xa = v2f{xcur.x, xcur.y}, xc = v2f{xcur.z, xcur.w};
        float g[4];
        #pragma unroll
        for (int r = 0; r < 4; ++r) {
            v2f acc = v2f{bm[r], 0.0f};
            acc = __builtin_elementwise_fma(wih2[r][0], xa, acc);
            acc = __builtin_elementwise_fma(wih2[r][1], xc, acc);
            #pragma unroll
            for (int k = 0; k < 5; ++k)
                acc = __builtin_elementwise_fma(wm2[r][k], hm2[k], acc);
            g[r] = acc.x + acc.y;
        }
        {
            float iv = sig2_(g[0]), fv = sig2_(g[1]), gv = tanh2_(g[2]), ov = sig2_(g[3]);
            cm = fmaf(fv, cm, iv * gv);
            float hn = ov * tanh2_(cm * K2L2E);
            s_h[slot][0][u] = hn;
        }
        __builtin_amdgcn_wave_barrier();
        {   // read back full h row 0 (wave-synchronous, conflict-free wide reads)
            float4 a = *(const float4*)&s_h[slot][0][0];
            float4 b = *(const float4*)&s_h[slot][0][4];
            float2 c = *(const float2*)&s_h[slot][0][8];
            hm2[0] = v2f{a.x, a.y}; hm2[1] = v2f{a.z, a.w};
            hm2[2] = v2f{b.x, b.y}; hm2[3] = v2f{b.z, b.w};
            hm2[4] = v2f{c.x, c.y};
        }

        // ---- rollout cells (folded weights) ----
        v2f hr2[5];
        #pragma unroll
        for (int k = 0; k < 5; ++k) hr2[k] = hm2[k];
        float cr = cm;
        #pragma unroll
        for (int p = 1; p < PN; ++p) {
            #pragma unroll
            for (int r = 0; r < 4; ++r) {
                v2f acc = v2f{br[r], 0.0f};
                #pragma unroll
                for (int k = 0; k < 5; ++k)
                    acc = __builtin_elementwise_fma(wc2[r][k], hr2[k], acc);
                g[r] = acc.x + acc.y;
            }
            float iv = sig2_(g[0]), fv = sig2_(g[1]), gv = tanh2_(g[2]), ov = sig2_(g[3]);
            cr = fmaf(fv, cr, iv * gv);
            float hn = ov * tanh2_(cr * K2L2E);
            s_h[slot][p][u] = hn;
            __builtin_amdgcn_wave_barrier();
            if (p < PN - 1) {
                float4 a = *(const float4*)&s_h[slot][p][0];
                float4 b = *(const float4*)&s_h[slot][p][4];
                float2 c = *(const float2*)&s_h[slot][p][8];
                hr2[0] = v2f{a.x, a.y}; hr2[1] = v2f{a.z, a.w};
                hr2[2] = v2f{b.x, b.y}; hr2[3] = v2f{b.z, b.w};
                hr2[4] = v2f{c.x, c.y};
            }
        }

        // ---- y phase: lane u -> y[pmine][opair..opair+1] ----
        {
            float4 a = *(const float4*)&s_h[slot][pmine][0];
            float4 b = *(const float4*)&s_h[slot][pmine][4];
            float2 c = *(const float2*)&s_h[slot][pmine][8];
            v2f h0 = v2f{a.x, a.y}, h1 = v2f{a.z, a.w};
            v2f h2 = v2f{b.x, b.y}, h3 = v2f{b.z, b.w};
            v2f h4 = v2f{c.x, c.y};
            v2f a0 = v2f{yb0, 0.0f}, a1 = v2f{yb1, 0.0f};
            a0 = __builtin_elementwise_fma(yl0[0], h0, a0);
            a1 = __builtin_elementwise_fma(yl1[0], h0, a1);
            a0 = __builtin_elementwise_fma(yl0[1], h1, a0);
            a1 = __builtin_elementwise_fma(yl1[1], h1, a1);
            a0 = __builtin_elementwise_fma(yl0[2], h2, a0);
            a1 = __builtin_elementwise_fma(yl1[2], h2, a1);
            a0 = __builtin_elementwise_fma(yl0[3], h3, a0);
            a1 = __builtin_elementwise_fma(yl1[3], h3, a1);
            a0 = __builtin_elementwise_fma(yl0[4], h4, a0);
            a1 = __builtin_elementwise_fma(yl1[4], h4, a1);
            float2 yv; yv.x = a0.x + a0.y; yv.y = a1.x + a1.y;
            *(float2*)(outb + t * PN * OUTN + 2 * u) = yv;
        }

        xcur = xnext;
    }

    // ---- final cell state c: [1, B, HID] appended after final_output ----
    out[(long)BN * TPN * PN * OUTN + (long)batch * HIDN + u] = cm;
}

extern "C" void kernel_launch(void* const* d_in, const int* in_sizes, int n_in,
                              void* d_out, int out_size, void* d_ws, size_t ws_size,
                              hipStream_t stream) {
    const float* x     = (const float*)d_in[0];
    const float* W_ih  = (const float*)d_in[1];
    const float* W_hh  = (const float*)d_in[2];
    const float* b_ih  = (const float*)d_in[3];
    const float* b_hh  = (const float*)d_in[4];
    const float* W_lin = (const float*)d_in[5];
    const float* b_lin = (const float*)d_in[6];
    float* out = (float*)d_out;

    const int grid = (BN + GPB - 1) / GPB;  // 683 blocks of 256 threads
    lstm_ar_kernel<<<grid, 256, 0, stream>>>(x, W_ih, W_hh, b_ih, b_hh, W_lin, b_lin, out);
}

// Round 3
// 198.997 us; speedup vs baseline: 1.2834x; 1.2531x over previous
//
#include <hip/hip_runtime.h>

// AutoregressiveLSTM: B=16384, T=100, HID=10, IN=OUT=4, P=5, Tp=96.
// Mapping: 10 lanes per batch element (lane u owns hidden unit u's 4 gate rows
// i,f,g,o), 6 groups/wave, 4 waves/block -> 24 batches per 256-thread block.
// Rollout cells use folded W_comb = W_hh + W_ih@W_lin (y off the critical path).
// Round 3: PIN all folded weights into VGPRs with opaque asm so the compiler
// cannot re-load them from global inside the time loop (rounds 1-2 had
// VGPR_Count 84/92 < the 126-float weight set -> per-iteration reloads).

#define HIDN 10
#define INPN 4
#define OUTN 4
#define PN   5
#define TN   100
#define TPN  96
#define BN   16384
#define GPB  24   // batches (groups) per 256-thread block

typedef float v2f __attribute__((ext_vector_type(2)));

#define PIN(x) asm volatile("" : "+v"(x))

__device__ __forceinline__ float rcpf_(float v) { return __builtin_amdgcn_rcpf(v); }
__device__ __forceinline__ float e2_(float v)   { return __builtin_amdgcn_exp2f(v); }
// g pre-scaled by log2(e):  sigmoid(x) = 1/(1+2^(-g))
__device__ __forceinline__ float sig2_(float g)  { return rcpf_(1.0f + e2_(-g)); }
// g pre-scaled by 2*log2(e): tanh(x) = 1 - 2/(1+2^g)
__device__ __forceinline__ float tanh2_(float g) { return fmaf(-2.0f, rcpf_(1.0f + e2_(g)), 1.0f); }

#define K2L2E 2.88539008177792681472f  // 2*log2(e), for tanh(c)

__global__ __launch_bounds__(256, 2) void lstm_ar_kernel(
    const float* __restrict__ x,      // [B, T, IN]
    const float* __restrict__ W_ih,   // [40, 4]
    const float* __restrict__ W_hh,   // [40, 10]
    const float* __restrict__ b_ih,   // [40]
    const float* __restrict__ b_hh,   // [40]
    const float* __restrict__ W_lin,  // [4, 10]
    const float* __restrict__ b_lin,  // [4]
    float* __restrict__ out)          // [B*Tp*P*OUT] ++ [B*HID]
{
    // h bank: row stride 20 floats (80B, 16B-aligned), slot stride 100 floats.
    __shared__ __align__(16) float s_h[GPB][PN][20];

    const int tid = threadIdx.x;
    const int wid = tid >> 6;
    const int wl  = tid & 63;
    const int grp = wl / 10;
    const int u   = wl - grp * 10;
    const int slot  = wid * 6 + grp;
    const int batch = blockIdx.x * GPB + slot;
    if (grp >= 6 || batch >= BN) return;

    // ---- build per-lane weight registers (rows u, u+10, u+20, u+30) ----
    const float L2E = 1.44269504088896340736f;
    const float rs[4] = { L2E, L2E, 2.0f * L2E, L2E };  // row pre-scales (i,f,g,o)

    v2f  wm2[4][5];   // scaled W_hh rows      (main cell)
    v2f  wc2[4][5];   // scaled W_comb rows    (rollout cells)
    v2f  wih2[4][2];  // scaled W_ih rows      (main cell)
    float bm[4], br[4];
    #pragma unroll
    for (int r = 0; r < 4; ++r) {
        const int j = u + r * 10;
        float wmr[HIDN], wihr[INPN];
        #pragma unroll
        for (int k = 0; k < HIDN; ++k) wmr[k] = W_hh[j * HIDN + k];
        #pragma unroll
        for (int q = 0; q < INPN; ++q) wihr[q] = W_ih[j * INPN + q];
        float bmr = b_ih[j] + b_hh[j];
        float brr = bmr;
        #pragma unroll
        for (int q = 0; q < INPN; ++q) brr += wihr[q] * b_lin[q];
        #pragma unroll
        for (int k = 0; k < HIDN; ++k) {
            float wck = wmr[k];
            #pragma unroll
            for (int q = 0; q < INPN; ++q) wck += wihr[q] * W_lin[q * HIDN + k];
            if (k & 1) {
                wm2[r][k >> 1].y = wmr[k] * rs[r];
                wc2[r][k >> 1].y = wck    * rs[r];
            } else {
                wm2[r][k >> 1].x = wmr[k] * rs[r];
                wc2[r][k >> 1].x = wck    * rs[r];
            }
        }
        #pragma unroll
        for (int q = 0; q < INPN; ++q) {
            if (q & 1) wih2[r][q >> 1].y = wihr[q] * rs[r];
            else       wih2[r][q >> 1].x = wihr[q] * rs[r];
        }
        bm[r] = bmr * rs[r];
        br[r] = brr * rs[r];
    }

    // ---- y weights in registers: lane outputs y[pmine][opair..opair+1] ----
    const int pmine = u >> 1;
    const int opair = (u & 1) * 2;
    v2f yl0[5], yl1[5];
    #pragma unroll
    for (int k = 0; k < HIDN; k += 2) {
        yl0[k >> 1] = v2f{ W_lin[opair * HIDN + k],        W_lin[opair * HIDN + k + 1] };
        yl1[k >> 1] = v2f{ W_lin[(opair + 1) * HIDN + k],  W_lin[(opair + 1) * HIDN + k + 1] };
    }
    float yb0 = b_lin[opair];
    float yb1 = b_lin[opair + 1];

    // ---- PIN every weight value into a VGPR (defeats re-load/remat) ----
    #pragma unroll
    for (int r = 0; r < 4; ++r) {
        #pragma unroll
        for (int k = 0; k < 5; ++k) { PIN(wm2[r][k]); PIN(wc2[r][k]); }
        PIN(wih2[r][0]); PIN(wih2[r][1]);
        PIN(bm[r]); PIN(br[r]);
    }
    #pragma unroll
    for (int k = 0; k < 5; ++k) { PIN(yl0[k]); PIN(yl1[k]); }
    PIN(yb0); PIN(yb1);

    const float* xb   = x + (long)batch * TN * INPN;
    float*       outb = out + (long)batch * TPN * PN * OUTN;

    v2f hm2[5];
    float cm = 0.0f;
    #pragma unroll
    for (int k = 0; k < 5; ++k) hm2[k] = v2f{0.0f, 0.0f};

    float4 xcur = *(const float4*)xb;
    for (int t = 0; t < TPN; ++t) {
        float4 xnext = *(const float4*)(xb + (t + 1) * INPN);  // t+1 <= 96 < T

        // ---- main cell ----
        v2f xa = v2f{xcur.x, xcur.y}, xc = v2f{xcur.z, xcur.w};
        float g[4];
        #pragma unroll
        for (int r = 0; r < 4; ++r) {
            v2f acc = v2f{bm[r], 0.0f};
            acc = __builtin_elementwise_fma(wih2[r][0], xa, acc);
            acc = __builtin_elementwise_fma(wih2[r][1], xc, acc);
            #pragma unroll
            for (int k = 0; k < 5; ++k)
                acc = __builtin_elementwise_fma(wm2[r][k], hm2[k], acc);
            g[r] = acc.x + acc.y;
        }
        {
            float iv = sig2_(g[0]), fv = sig2_(g[1]), gv = tanh2_(g[2]), ov = sig2_(g[3]);
            cm = fmaf(fv, cm, iv * gv);
            float hn = ov * tanh2_(cm * K2L2E);
            s_h[slot][0][u] = hn;
        }
        __builtin_amdgcn_wave_barrier();
        {   // read back full h row 0 (wave-synchronous wide reads)
            float4 a = *(const float4*)&s_h[slot][0][0];
            float4 b = *(const float4*)&s_h[slot][0][4];
            float2 c = *(const float2*)&s_h[slot][0][8];
            hm2[0] = v2f{a.x, a.y}; hm2[1] = v2f{a.z, a.w};
            hm2[2] = v2f{b.x, b.y}; hm2[3] = v2f{b.z, b.w};
            hm2[4] = v2f{c.x, c.y};
        }

        // ---- rollout cells (folded weights) ----
        v2f hr2[5];
        #pragma unroll
        for (int k = 0; k < 5; ++k) hr2[k] = hm2[k];
        float cr = cm;
        #pragma unroll
        for (int p = 1; p < PN; ++p) {
            #pragma unroll
            for (int r = 0; r < 4; ++r) {
                v2f acc = v2f{br[r], 0.0f};
                #pragma unroll
                for (int k = 0; k < 5; ++k)
                    acc = __builtin_elementwise_fma(wc2[r][k], hr2[k], acc);
                g[r] = acc.x + acc.y;
            }
            float iv = sig2_(g[0]), fv = sig2_(g[1]), gv = tanh2_(g[2]), ov = sig2_(g[3]);
            cr = fmaf(fv, cr, iv * gv);
            float hn = ov * tanh2_(cr * K2L2E);
            s_h[slot][p][u] = hn;
            __builtin_amdgcn_wave_barrier();
            if (p < PN - 1) {
                float4 a = *(const float4*)&s_h[slot][p][0];
                float4 b = *(const float4*)&s_h[slot][p][4];
                float2 c = *(const float2*)&s_h[slot][p][8];
                hr2[0] = v2f{a.x, a.y}; hr2[1] = v2f{a.z, a.w};
                hr2[2] = v2f{b.x, b.y}; hr2[3] = v2f{b.z, b.w};
                hr2[4] = v2f{c.x, c.y};
            }
        }

        // ---- y phase: lane u -> y[pmine][opair..opair+1] ----
        {
            float4 a = *(const float4*)&s_h[slot][pmine][0];
            float4 b = *(const float4*)&s_h[slot][pmine][4];
            float2 c = *(const float2*)&s_h[slot][pmine][8];
            v2f h0 = v2f{a.x, a.y}, h1 = v2f{a.z, a.w};
            v2f h2 = v2f{b.x, b.y}, h3 = v2f{b.z, b.w};
            v2f h4 = v2f{c.x, c.y};
            v2f a0 = v2f{yb0, 0.0f}, a1 = v2f{yb1, 0.0f};
            a0 = __builtin_elementwise_fma(yl0[0], h0, a0);
            a1 = __builtin_elementwise_fma(yl1[0], h0, a1);
            a0 = __builtin_elementwise_fma(yl0[1], h1, a0);
            a1 = __builtin_elementwise_fma(yl1[1], h1, a1);
            a0 = __builtin_elementwise_fma(yl0[2], h2, a0);
            a1 = __builtin_elementwise_fma(yl1[2], h2, a1);
            a0 = __builtin_elementwise_fma(yl0[3], h3, a0);
            a1 = __builtin_elementwise_fma(yl1[3], h3, a1);
            a0 = __builtin_elementwise_fma(yl0[4], h4, a0);
            a1 = __builtin_elementwise_fma(yl1[4], h4, a1);
            float2 yv; yv.x = a0.x + a0.y; yv.y = a1.x + a1.y;
            *(float2*)(outb + t * PN * OUTN + 2 * u) = yv;
        }

        xcur = xnext;
    }

    // ---- final cell state c: [1, B, HID] appended after final_output ----
    out[(long)BN * TPN * PN * OUTN + (long)batch * HIDN + u] = cm;
}

extern "C" void kernel_launch(void* const* d_in, const int* in_sizes, int n_in,
                              void* d_out, int out_size, void* d_ws, size_t ws_size,
                              hipStream_t stream) {
    const float* x     = (const float*)d_in[0];
    const float* W_ih  = (const float*)d_in[1];
    const float* W_hh  = (const float*)d_in[2];
    const float* b_ih  = (const float*)d_in[3];
    const float* b_hh  = (const float*)d_in[4];
    const float* W_lin = (const float*)d_in[5];
    const float* b_lin = (const float*)d_in[6];
    float* out = (float*)d_out;

    const int grid = (BN + GPB - 1) / GPB;  // 683 blocks of 256 threads
    lstm_ar_kernel<<<grid, 256, 0, stream>>>(x, W_ih, W_hh, b_ih, b_hh, W_lin, b_lin, out);
}

// Round 4
// 198.898 us; speedup vs baseline: 1.2840x; 1.0005x over previous
//
#include <hip/hip_runtime.h>

// AutoregressiveLSTM: B=16384, T=100, HID=10, IN=OUT=4, P=5, Tp=96.
// Mapping: 10 lanes per batch element (lane u owns hidden unit u's 4 gate rows
// i,f,g,o), 6 groups/wave, 4 waves/block -> 24 batches per 256-thread block.
// Rollout cells use folded W_comb = W_hh + W_ih@W_lin (y off the critical path).
// Round 4: __launch_bounds__(256, 1). Round 3 kept weights resident but in
// AGPRs (VGPR_Count=92 < 126-float weight set) -> ~258 v_accvgpr_read/step.
// waves_per_eu=1 lifts the unified-register budget so the ~200-value working
// set fits in ARCH VGPRs; usage ~230 < 256 keeps 2 waves/SIMD residency.

#define HIDN 10
#define INPN 4
#define OUTN 4
#define PN   5
#define TN   100
#define TPN  96
#define BN   16384
#define GPB  24   // batches (groups) per 256-thread block

typedef float v2f __attribute__((ext_vector_type(2)));

#define PIN(x) asm volatile("" : "+v"(x))

__device__ __forceinline__ float rcpf_(float v) { return __builtin_amdgcn_rcpf(v); }
__device__ __forceinline__ float e2_(float v)   { return __builtin_amdgcn_exp2f(v); }
// g pre-scaled by log2(e):  sigmoid(x) = 1/(1+2^(-g))
__device__ __forceinline__ float sig2_(float g)  { return rcpf_(1.0f + e2_(-g)); }
// g pre-scaled by 2*log2(e): tanh(x) = 1 - 2/(1+2^g)
__device__ __forceinline__ float tanh2_(float g) { return fmaf(-2.0f, rcpf_(1.0f + e2_(g)), 1.0f); }

#define K2L2E 2.88539008177792681472f  // 2*log2(e), for tanh(c)

__global__ __launch_bounds__(256, 1) void lstm_ar_kernel(
    const float* __restrict__ x,      // [B, T, IN]
    const float* __restrict__ W_ih,   // [40, 4]
    const float* __restrict__ W_hh,   // [40, 10]
    const float* __restrict__ b_ih,   // [40]
    const float* __restrict__ b_hh,   // [40]
    const float* __restrict__ W_lin,  // [4, 10]
    const float* __restrict__ b_lin,  // [4]
    float* __restrict__ out)          // [B*Tp*P*OUT] ++ [B*HID]
{
    // h bank: row stride 20 floats (80B, 16B-aligned), slot stride 100 floats.
    __shared__ __align__(16) float s_h[GPB][PN][20];

    const int tid = threadIdx.x;
    const int wid = tid >> 6;
    const int wl  = tid & 63;
    const int grp = wl / 10;
    const int u   = wl - grp * 10;
    const int slot  = wid * 6 + grp;
    const int batch = blockIdx.x * GPB + slot;
    if (grp >= 6 || batch >= BN) return;

    // ---- build per-lane weight registers (rows u, u+10, u+20, u+30) ----
    const float L2E = 1.44269504088896340736f;
    const float rs[4] = { L2E, L2E, 2.0f * L2E, L2E };  // row pre-scales (i,f,g,o)

    v2f  wm2[4][5];   // scaled W_hh rows      (main cell)
    v2f  wc2[4][5];   // scaled W_comb rows    (rollout cells)
    v2f  wih2[4][2];  // scaled W_ih rows      (main cell)
    float bm[4], br[4];
    #pragma unroll
    for (int r = 0; r < 4; ++r) {
        const int j = u + r * 10;
        float wmr[HIDN], wihr[INPN];
        #pragma unroll
        for (int k = 0; k < HIDN; ++k) wmr[k] = W_hh[j * HIDN + k];
        #pragma unroll
        for (int q = 0; q < INPN; ++q) wihr[q] = W_ih[j * INPN + q];
        float bmr = b_ih[j] + b_hh[j];
        float brr = bmr;
        #pragma unroll
        for (int q = 0; q < INPN; ++q) brr += wihr[q] * b_lin[q];
        #pragma unroll
        for (int k = 0; k < HIDN; ++k) {
            float wck = wmr[k];
            #pragma unroll
            for (int q = 0; q < INPN; ++q) wck += wihr[q] * W_lin[q * HIDN + k];
            if (k & 1) {
                wm2[r][k >> 1].y = wmr[k] * rs[r];
                wc2[r][k >> 1].y = wck    * rs[r];
            } else {
                wm2[r][k >> 1].x = wmr[k] * rs[r];
                wc2[r][k >> 1].x = wck    * rs[r];
            }
        }
        #pragma unroll
        for (int q = 0; q < INPN; ++q) {
            if (q & 1) wih2[r][q >> 1].y = wihr[q] * rs[r];
            else       wih2[r][q >> 1].x = wihr[q] * rs[r];
        }
        bm[r] = bmr * rs[r];
        br[r] = brr * rs[r];
    }

    // ---- y weights in registers: lane outputs y[pmine][opair..opair+1] ----
    const int pmine = u >> 1;
    const int opair = (u & 1) * 2;
    v2f yl0[5], yl1[5];
    #pragma unroll
    for (int k = 0; k < HIDN; k += 2) {
        yl0[k >> 1] = v2f{ W_lin[opair * HIDN + k],        W_lin[opair * HIDN + k + 1] };
        yl1[k >> 1] = v2f{ W_lin[(opair + 1) * HIDN + k],  W_lin[(opair + 1) * HIDN + k + 1] };
    }
    float yb0 = b_lin[opair];
    float yb1 = b_lin[opair + 1];

    // ---- PIN every weight value into a register (defeats re-load/remat) ----
    #pragma unroll
    for (int r = 0; r < 4; ++r) {
        #pragma unroll
        for (int k = 0; k < 5; ++k) { PIN(wm2[r][k]); PIN(wc2[r][k]); }
        PIN(wih2[r][0]); PIN(wih2[r][1]);
        PIN(bm[r]); PIN(br[r]);
    }
    #pragma unroll
    for (int k = 0; k < 5; ++k) { PIN(yl0[k]); PIN(yl1[k]); }
    PIN(yb0); PIN(yb1);

    const float* xb   = x + (long)batch * TN * INPN;
    float*       outb = out + (long)batch * TPN * PN * OUTN;

    v2f hm2[5];
    float cm = 0.0f;
    #pragma unroll
    for (int k = 0; k < 5; ++k) hm2[k] = v2f{0.0f, 0.0f};

    float4 xcur = *(const float4*)xb;
    for (int t = 0; t < TPN; ++t) {
        float4 xnext = *(const float4*)(xb + (t + 1) * INPN);  // t+1 <= 96 < T

        // ---- main cell ----
        v2f xa = v2f{xcur.x, xcur.y}, xc = v2f{xcur.z, xcur.w};
        float g[4];
        #pragma unroll
        for (int r = 0; r < 4; ++r) {
            v2f acc = v2f{bm[r], 0.0f};
            acc = __builtin_elementwise_fma(wih2[r][0], xa, acc);
            acc = __builtin_elementwise_fma(wih2[r][1], xc, acc);
            #pragma unroll
            for (int k = 0; k < 5; ++k)
                acc = __builtin_elementwise_fma(wm2[r][k], hm2[k], acc);
            g[r] = acc.x + acc.y;
        }
        {
            float iv = sig2_(g[0]), fv = sig2_(g[1]), gv = tanh2_(g[2]), ov = sig2_(g[3]);
            cm = fmaf(fv, cm, iv * gv);
            float hn = ov * tanh2_(cm * K2L2E);
            s_h[slot][0][u] = hn;
        }
        __builtin_amdgcn_wave_barrier();
        {   // read back full h row 0 (wave-synchronous wide reads)
            float4 a = *(const float4*)&s_h[slot][0][0];
            float4 b = *(const float4*)&s_h[slot][0][4];
            float2 c = *(const float2*)&s_h[slot][0][8];
            hm2[0] = v2f{a.x, a.y}; hm2[1] = v2f{a.z, a.w};
            hm2[2] = v2f{b.x, b.y}; hm2[3] = v2f{b.z, b.w};
            hm2[4] = v2f{c.x, c.y};
        }

        // ---- rollout cells (folded weights) ----
        v2f hr2[5];
        #pragma unroll
        for (int k = 0; k < 5; ++k) hr2[k] = hm2[k];
        float cr = cm;
        #pragma unroll
        for (int p = 1; p < PN; ++p) {
            #pragma unroll
            for (int r = 0; r < 4; ++r) {
                v2f acc = v2f{br[r], 0.0f};
                #pragma unroll
                for (int k = 0; k < 5; ++k)
                    acc = __builtin_elementwise_fma(wc2[r][k], hr2[k], acc);
                g[r] = acc.x + acc.y;
            }
            float iv = sig2_(g[0]), fv = sig2_(g[1]), gv = tanh2_(g[2]), ov = sig2_(g[3]);
            cr = fmaf(fv, cr, iv * gv);
            float hn = ov * tanh2_(cr * K2L2E);
            s_h[slot][p][u] = hn;
            __builtin_amdgcn_wave_barrier();
            if (p < PN - 1) {
                float4 a = *(const float4*)&s_h[slot][p][0];
                float4 b = *(const float4*)&s_h[slot][p][4];
                float2 c = *(const float2*)&s_h[slot][p][8];
                hr2[0] = v2f{a.x, a.y}; hr2[1] = v2f{a.z, a.w};
                hr2[2] = v2f{b.x, b.y}; hr2[3] = v2f{b.z, b.w};
                hr2[4] = v2f{c.x, c.y};
            }
        }

        // ---- y phase: lane u -> y[pmine][opair..opair+1] ----
        {
            float4 a = *(const float4*)&s_h[slot][pmine][0];
            float4 b = *(const float4*)&s_h[slot][pmine][4];
            float2 c = *(const float2*)&s_h[slot][pmine][8];
            v2f h0 = v2f{a.x, a.y}, h1 = v2f{a.z, a.w};
            v2f h2 = v2f{b.x, b.y}, h3 = v2f{b.z, b.w};
            v2f h4 = v2f{c.x, c.y};
            v2f a0 = v2f{yb0, 0.0f}, a1 = v2f{yb1, 0.0f};
            a0 = __builtin_elementwise_fma(yl0[0], h0, a0);
            a1 = __builtin_elementwise_fma(yl1[0], h0, a1);
            a0 = __builtin_elementwise_fma(yl0[1], h1, a0);
            a1 = __builtin_elementwise_fma(yl1[1], h1, a1);
            a0 = __builtin_elementwise_fma(yl0[2], h2, a0);
            a1 = __builtin_elementwise_fma(yl1[2], h2, a1);
            a0 = __builtin_elementwise_fma(yl0[3], h3, a0);
            a1 = __builtin_elementwise_fma(yl1[3], h3, a1);
            a0 = __builtin_elementwise_fma(yl0[4], h4, a0);
            a1 = __builtin_elementwise_fma(yl1[4], h4, a1);
            float2 yv; yv.x = a0.x + a0.y; yv.y = a1.x + a1.y;
            *(float2*)(outb + t * PN * OUTN + 2 * u) = yv;
        }

        xcur = xnext;
    }

    // ---- final cell state c: [1, B, HID] appended after final_output ----
    out[(long)BN * TPN * PN * OUTN + (long)batch * HIDN + u] = cm;
}

extern "C" void kernel_launch(void* const* d_in, const int* in_sizes, int n_in,
                              void* d_out, int out_size, void* d_ws, size_t ws_size,
                              hipStream_t stream) {
    const float* x     = (const float*)d_in[0];
    const float* W_ih  = (const float*)d_in[1];
    const float* W_hh  = (const float*)d_in[2];
    const float* b_ih  = (const float*)d_in[3];
    const float* b_hh  = (const float*)d_in[4];
    const float* W_lin = (const float*)d_in[5];
    const float* b_lin = (const float*)d_in[6];
    float* out = (float*)d_out;

    const int grid = (BN + GPB - 1) / GPB;  // 683 blocks of 256 threads
    lstm_ar_kernel<<<grid, 256, 0, stream>>>(x, W_ih, W_hh, b_ih, b_hh, W_lin, b_lin, out);
}

// Round 5
// 185.653 us; speedup vs baseline: 1.3756x; 1.0713x over previous
//
#include <hip/hip_runtime.h>

// AutoregressiveLSTM: B=16384, T=100, HID=10, IN=OUT=4, P=5, Tp=96.
// Mapping: 10 lanes per batch element (lane u owns hidden unit u's 4 gate rows
// i,f,g,o), 6 groups/wave, 4 waves/block -> 24 batches per 256-thread block.
// Round 5: ALL cells (main + rollout) use the folded W_comb = W_hh + W_ih@W_lin;
// the main cell applies a rank-4 input correction wih@(x_t - y_prev) where
// y_prev = W_lin@h_{t-1}+b_lin is the previous step's p=0 output (mirrored to
// LDS by lanes 0-1). This deletes the 40-reg wm set -> ~135-reg working set,
// letting the allocator keep everything in arch VGPRs and fit 3 blocks/CU
// (all 683 blocks resident in one round, no tail).

#define HIDN 10
#define INPN 4
#define OUTN 4
#define PN   5
#define TN   100
#define TPN  96
#define BN   16384
#define GPB  24   // batches (groups) per 256-thread block

typedef float v2f __attribute__((ext_vector_type(2)));

#define PIN(x) asm volatile("" : "+v"(x))

__device__ __forceinline__ float rcpf_(float v) { return __builtin_amdgcn_rcpf(v); }
__device__ __forceinline__ float e2_(float v)   { return __builtin_amdgcn_exp2f(v); }
// g pre-scaled by log2(e):  sigmoid(x) = 1/(1+2^(-g))
__device__ __forceinline__ float sig2_(float g)  { return rcpf_(1.0f + e2_(-g)); }
// g pre-scaled by 2*log2(e): tanh(x) = 1 - 2/(1+2^g)
__device__ __forceinline__ float tanh2_(float g) { return fmaf(-2.0f, rcpf_(1.0f + e2_(g)), 1.0f); }

#define K2L2E 2.88539008177792681472f  // 2*log2(e), for tanh(c)

__global__ __launch_bounds__(256, 3) void lstm_ar_kernel(
    const float* __restrict__ x,      // [B, T, IN]
    const float* __restrict__ W_ih,   // [40, 4]
    const float* __restrict__ W_hh,   // [40, 10]
    const float* __restrict__ b_ih,   // [40]
    const float* __restrict__ b_hh,   // [40]
    const float* __restrict__ W_lin,  // [4, 10]
    const float* __restrict__ b_lin,  // [4]
    float* __restrict__ out)          // [B*Tp*P*OUT] ++ [B*HID]
{
    // h bank: row stride 20 floats (80B), slot stride 100 floats (25 banks ->
    // 6 groups/wave land on disjoint bank quads for the wide row reads).
    __shared__ __align__(16) float s_h[GPB][PN][20];
    __shared__ __align__(16) float s_y[GPB][4];   // y_prev (p=0 output) per slot

    const int tid = threadIdx.x;
    const int wid = tid >> 6;
    const int wl  = tid & 63;
    const int grp = wl / 10;
    const int u   = wl - grp * 10;
    const int slot  = wid * 6 + grp;
    const int batch = blockIdx.x * GPB + slot;
    if (grp >= 6 || batch >= BN) return;

    // ---- build per-lane folded weights (rows u, u+10, u+20, u+30) ----
    const float L2E = 1.44269504088896340736f;
    const float rs[4] = { L2E, L2E, 2.0f * L2E, L2E };  // pre-scales (i,f,g,o)

    v2f  wc2[4][5];   // scaled W_comb rows = W_hh + W_ih@W_lin
    v2f  wih2[4][2];  // scaled W_ih rows (input-correction term)
    v2f  br2[4];      // {scaled folded bias, 0}
    #pragma unroll
    for (int r = 0; r < 4; ++r) {
        const int j = u + r * 10;
        float wihr[INPN];
        #pragma unroll
        for (int q = 0; q < INPN; ++q) wihr[q] = W_ih[j * INPN + q];
        float brr = b_ih[j] + b_hh[j];
        #pragma unroll
        for (int q = 0; q < INPN; ++q) brr += wihr[q] * b_lin[q];
        #pragma unroll
        for (int k = 0; k < HIDN; ++k) {
            float wck = W_hh[j * HIDN + k];
            #pragma unroll
            for (int q = 0; q < INPN; ++q) wck += wihr[q] * W_lin[q * HIDN + k];
            if (k & 1) wc2[r][k >> 1].y = wck * rs[r];
            else       wc2[r][k >> 1].x = wck * rs[r];
        }
        #pragma unroll
        for (int q = 0; q < INPN; ++q) {
            if (q & 1) wih2[r][q >> 1].y = wihr[q] * rs[r];
            else       wih2[r][q >> 1].x = wihr[q] * rs[r];
        }
        br2[r] = v2f{ brr * rs[r], 0.0f };
    }

    // ---- y weights: lane u outputs y[pmine][opair..opair+1] ----
    const int pmine = u >> 1;
    const int opair = (u & 1) * 2;
    v2f yl0[5], yl1[5];
    #pragma unroll
    for (int k = 0; k < HIDN; k += 2) {
        yl0[k >> 1] = v2f{ W_lin[opair * HIDN + k],        W_lin[opair * HIDN + k + 1] };
        yl1[k >> 1] = v2f{ W_lin[(opair + 1) * HIDN + k],  W_lin[(opair + 1) * HIDN + k + 1] };
    }
    v2f ybv0 = v2f{ b_lin[opair],     0.0f };
    v2f ybv1 = v2f{ b_lin[opair + 1], 0.0f };

    // ---- pin weights (defeat re-load/remat inside the loop) ----
    #pragma unroll
    for (int r = 0; r < 4; ++r) {
        #pragma unroll
        for (int k = 0; k < 5; ++k) PIN(wc2[r][k]);
        PIN(wih2[r][0]); PIN(wih2[r][1]); PIN(br2[r]);
    }
    #pragma unroll
    for (int k = 0; k < 5; ++k) { PIN(yl0[k]); PIN(yl1[k]); }
    PIN(ybv0); PIN(ybv1);

    // ---- init recurrent LDS state: h = 0, y_prev = b_lin ----
    s_h[slot][0][u] = 0.0f;
    if (u < 4) s_y[slot][u] = b_lin[u];
    __builtin_amdgcn_wave_barrier();

    const float* xb   = x + (long)batch * TN * INPN;
    float*       outb = out + (long)batch * TPN * PN * OUTN;

    float cm = 0.0f;
    float4 xcur = *(const float4*)xb;
    for (int t = 0; t < TPN; ++t) {
        float4 xnext = *(const float4*)(xb + (t + 1) * INPN);  // t+1 <= 96 < T

        v2f h2[5];
        float g[4];

        // ---- main cell: gates = wc@h + br + wih@(x - y_prev) ----
        {
            float4 yp = *(const float4*)&s_y[slot][0];
            float4 a  = *(const float4*)&s_h[slot][0][0];
            float4 b  = *(const float4*)&s_h[slot][0][4];
            float2 c2 = *(const float2*)&s_h[slot][0][8];
            h2[0] = v2f{a.x, a.y}; h2[1] = v2f{a.z, a.w};
            h2[2] = v2f{b.x, b.y}; h2[3] = v2f{b.z, b.w};
            h2[4] = v2f{c2.x, c2.y};
            v2f dxa = v2f{xcur.x - yp.x, xcur.y - yp.y};
            v2f dxc = v2f{xcur.z - yp.z, xcur.w - yp.w};
            #pragma unroll
            for (int r = 0; r < 4; ++r) {
                v2f acc = br2[r];
                acc = __builtin_elementwise_fma(wih2[r][0], dxa, acc);
                acc = __builtin_elementwise_fma(wih2[r][1], dxc, acc);
                #pragma unroll
                for (int k = 0; k < 5; ++k)
                    acc = __builtin_elementwise_fma(wc2[r][k], h2[k], acc);
                g[r] = acc.x + acc.y;
            }
            float iv = sig2_(g[0]), fv = sig2_(g[1]), gv = tanh2_(g[2]), ov = sig2_(g[3]);
            cm = fmaf(fv, cm, iv * gv);
            float hn = ov * tanh2_(cm * K2L2E);
            s_h[slot][0][u] = hn;   // h_t overwrites h_{t-1}
        }
        __builtin_amdgcn_wave_barrier();

        // ---- rollout cells p=1..4: gates = wc@h_{p-1} + br ----
        float cr = cm;
        #pragma unroll
        for (int p = 1; p < PN; ++p) {
            float4 a  = *(const float4*)&s_h[slot][p - 1][0];
            float4 b  = *(const float4*)&s_h[slot][p - 1][4];
            float2 c2 = *(const float2*)&s_h[slot][p - 1][8];
            h2[0] = v2f{a.x, a.y}; h2[1] = v2f{a.z, a.w};
            h2[2] = v2f{b.x, b.y}; h2[3] = v2f{b.z, b.w};
            h2[4] = v2f{c2.x, c2.y};
            #pragma unroll
            for (int r = 0; r < 4; ++r) {
                v2f acc = br2[r];
                #pragma unroll
                for (int k = 0; k < 5; ++k)
                    acc = __builtin_elementwise_fma(wc2[r][k], h2[k], acc);
                g[r] = acc.x + acc.y;
            }
            float iv = sig2_(g[0]), fv = sig2_(g[1]), gv = tanh2_(g[2]), ov = sig2_(g[3]);
            cr = fmaf(fv, cr, iv * gv);
            float hn = ov * tanh2_(cr * K2L2E);
            s_h[slot][p][u] = hn;
            __builtin_amdgcn_wave_barrier();
        }

        // ---- y phase: lane u -> y[pmine][opair..opair+1] ----
        {
            float4 a  = *(const float4*)&s_h[slot][pmine][0];
            float4 b  = *(const float4*)&s_h[slot][pmine][4];
            float2 c2 = *(const float2*)&s_h[slot][pmine][8];
            v2f h0 = v2f{a.x, a.y},  h1 = v2f{a.z, a.w};
            v2f h3 = v2f{b.x, b.y},  h4 = v2f{b.z, b.w};
            v2f h5 = v2f{c2.x, c2.y};
            v2f a0 = ybv0, a1 = ybv1;
            a0 = __builtin_elementwise_fma(yl0[0], h0, a0);
            a1 = __builtin_elementwise_fma(yl1[0], h0, a1);
            a0 = __builtin_elementwise_fma(yl0[1], h1, a0);
            a1 = __builtin_elementwise_fma(yl1[1], h1, a1);
            a0 = __builtin_elementwise_fma(yl0[2], h3, a0);
            a1 = __builtin_elementwise_fma(yl1[2], h3, a1);
            a0 = __builtin_elementwise_fma(yl0[3], h4, a0);
            a1 = __builtin_elementwise_fma(yl1[3], h4, a1);
            a0 = __builtin_elementwise_fma(yl0[4], h5, a0);
            a1 = __builtin_elementwise_fma(yl1[4], h5, a1);
            float2 yv; yv.x = a0.x + a0.y; yv.y = a1.x + a1.y;
            *(float2*)(outb + t * PN * OUTN + 2 * u) = yv;
            // lanes 0-1 mirror y[t][p=0] into s_y for the next main cell
            if (u < 2) *(float2*)&s_y[slot][2 * u] = yv;
        }
        __builtin_amdgcn_wave_barrier();

        xcur = xnext;
    }

    // ---- final cell state c: [1, B, HID] appended after final_output ----
    out[(long)BN * TPN * PN * OUTN + (long)batch * HIDN + u] = cm;
}

extern "C" void kernel_launch(void* const* d_in, const int* in_sizes, int n_in,
                              void* d_out, int out_size, void* d_ws, size_t ws_size,
                              hipStream_t stream) {
    const float* x     = (const float*)d_in[0];
    const float* W_ih  = (const float*)d_in[1];
    const float* W_hh  = (const float*)d_in[2];
    const float* b_ih  = (const float*)d_in[3];
    const float* b_hh  = (const float*)d_in[4];
    const float* W_lin = (const float*)d_in[5];
    const float* b_lin = (const float*)d_in[6];
    float* out = (float*)d_out;

    const int grid = (BN + GPB - 1) / GPB;  // 683 blocks of 256 threads
    lstm_ar_kernel<<<grid, 256, 0, stream>>>(x, W_ih, W_hh, b_ih, b_hh, W_lin, b_lin, out);
}